// Round 23
// baseline (459.488 us; speedup 1.0000x reference)
//
#include <hip/hip_runtime.h>
#include <cstdint>
#include <cstddef>

#define DEVFN __device__ __forceinline__

typedef __attribute__((ext_vector_type(8))) short short8;
typedef __attribute__((ext_vector_type(4))) float f32x4;
typedef __attribute__((ext_vector_type(2))) long long2v;

// async global->LDS, 16B per lane; LDS dest = wave-uniform base + lane*16
#define GLOAD_LDS16(gaddr, laddr)                                              \
  __builtin_amdgcn_global_load_lds(                                            \
      (const __attribute__((address_space(1))) uint32_t*)(gaddr),              \
      (__attribute__((address_space(3))) uint32_t*)(laddr), 16, 0, 0)

// Problem constants
constexpr int B_ = 64, T_ = 197, DIM_ = 768, H_ = 12, HD_ = 64, MLP_ = 3072;
constexpr int N_ = B_ * T_;          // 12608 tokens
constexpr int NE_ = 99, NO_ = 98, REFF_ = 16;
constexpr int TM_ = (NE_ - REFF_) + NO_;  // 181 merged tokens
constexpr int NM_ = B_ * TM_;        // 11584 merged rows

// ---------------- workspace layout (BYTE offsets; all 16B-aligned) ----------------
constexpr size_t BOFF_A    = 0;
constexpr size_t BOFF_GBC  = 0;            // gbc fp8: 35.6MB, overlays dead A region
constexpr size_t BOFF_B    = 58097664;     // h8 fp8 [9.68MB] then o8 fp8 [9.68MB]
constexpr size_t BOFF_O8   = 67780608;     // = BOFF_B + N_*DIM_
constexpr size_t BOFF_C    = 77463552;
constexpr size_t BOFF_D    = 113049600;    // met fp32 then h2 fp8 (disjoint lifetimes)
constexpr size_t BOFF_WKM  = 130842624;
constexpr size_t BOFF_RT   = 131039232;
constexpr size_t BOFF_NSZ  = 131873280;
constexpr size_t BOFF_WQB  = 131919616;    // fp8 wqkv
constexpr size_t BOFF_WPB  = 135458560;    // fp8 wproj
constexpr size_t BOFF_W1B  = 136638208;    // fp8
constexpr size_t BOFF_W2B  = 141356800;    // fp8

// ---------------- bf16 helpers ----------------
DEVFN ushort f2b(float f) {
  union { float f; uint u; } c; c.f = f;
  uint u = c.u;
  u = (u + 0x7FFFu + ((u >> 16) & 1u)) >> 16;
  return (ushort)u;
}
DEVFN float b2f(ushort h) {
  union { uint u; float f; } c; c.u = ((uint)h) << 16;
  return c.f;
}
// fp8 e4m3 (OCP) converts via HW
DEVFN uchar f2e4m3(float v) {
  return (uchar)__builtin_amdgcn_cvt_pk_fp8_f32(v, 0.f, 0, false);
}
DEVFN uint pk4_fp8(float a, float b, float c, float d) {
  int r = __builtin_amdgcn_cvt_pk_fp8_f32(a, b, 0, false);
  r = __builtin_amdgcn_cvt_pk_fp8_f32(c, d, r, true);
  return (uint)r;
}

// fast GELU (tanh form), clamped
DEVFN float fast_gelu(float x) {
  float x3 = x * x * x;
  float z2 = 2.0f * 0.7978845608028654f * fmaf(0.044715f, x3, x);
  z2 = fminf(fmaxf(z2, -60.0f), 60.0f);
  float e = __expf(z2);
  float th = (e - 1.0f) / (e + 1.0f);
  return 0.5f * x * (1.0f + th);
}

// ---------------- reductions ----------------
DEVFN float wave_sum(float v) {
#pragma unroll
  for (int o = 32; o; o >>= 1) v += __shfl_down(v, o, 64);
  return v;
}
DEVFN float block_sum(float v, float* red) {
  v = wave_sum(v);
  int lane = threadIdx.x & 63, wid = threadIdx.x >> 6;
  __syncthreads();
  if (lane == 0) red[wid] = v;
  __syncthreads();
  return red[0] + red[1] + red[2] + red[3];
}

// ------- fused weight conversion: all four weights -> fp8 ----------------------------
constexpr int SEG0 = 3 * DIM_ * DIM_;
constexpr int SEG1 = SEG0 + DIM_ * DIM_;
constexpr int SEG2 = SEG1 + MLP_ * DIM_;
constexpr int SEG3 = SEG2 + DIM_ * MLP_;
__global__ __launch_bounds__(256) void f2ball_kernel(
    const float* __restrict__ s0, const float* __restrict__ s1,
    const float* __restrict__ s2, const float* __restrict__ s3,
    uchar* __restrict__ d0, uchar* __restrict__ d1,
    uchar* __restrict__ d2, uchar* __restrict__ d3) {
  int i = (blockIdx.x * 256 + threadIdx.x) * 4;
  if (i >= SEG3) return;
  const float* src; uchar* dst; int off;
  if (i < SEG0)      { src = s0; dst = d0; off = i; }
  else if (i < SEG1) { src = s1; dst = d1; off = i - SEG0; }
  else if (i < SEG2) { src = s2; dst = d2; off = i - SEG1; }
  else               { src = s3; dst = d3; off = i - SEG2; }
  float4 v = *reinterpret_cast<const float4*>(src + off);
  *reinterpret_cast<uint*>(dst + off) = pk4_fp8(v.x, v.y, v.z, v.w);
}

// ---------------- LayerNorm: fp32 + fp8 outputs (LN1) ----------------
__global__ __launch_bounds__(256) void ln_kernel(
    const float* __restrict__ x, const float* __restrict__ g,
    const float* __restrict__ bb, float* __restrict__ outf,
    uchar* __restrict__ out8) {
  __shared__ float red[4];
  size_t row = blockIdx.x;
  const float* xr = x + row * DIM_;
  int tid = threadIdx.x;
  float s = 0.f;
  for (int i = tid; i < DIM_; i += 256) s += xr[i];
  s = block_sum(s, red);
  float mean = s * (1.0f / DIM_);
  float vs = 0.f;
  for (int i = tid; i < DIM_; i += 256) { float d = xr[i] - mean; vs = fmaf(d, d, vs); }
  vs = block_sum(vs, red);
  float rstd = rsqrtf(vs * (1.0f / DIM_) + 1e-5f);
  for (int i = tid; i < DIM_; i += 256) {
    float v = (xr[i] - mean) * rstd * g[i] + bb[i];
    if (outf) outf[row * DIM_ + i] = v;
    out8[row * DIM_ + i] = f2e4m3(v);
  }
}

// ---------------- head-averaged K weights ----------------
__global__ __launch_bounds__(256) void wkmean_kernel(const float* __restrict__ wqkv,
                                                     float* __restrict__ wkm) {
  int idx = blockIdx.x * 256 + threadIdx.x;
  if (idx >= HD_ * DIM_) return;
  int d = idx / DIM_, c = idx % DIM_;
  float s = 0.f;
  for (int h2 = 0; h2 < H_; h2++) s += wqkv[(size_t)(DIM_ + h2 * HD_ + d) * DIM_ + c];
  wkm[idx] = s * (1.0f / H_);
}

// ---------------- fp32 GEMM (kept for the index-deciding metric path) ----------------
__global__ __launch_bounds__(256) void gemm_bt(
    const float* __restrict__ A, const float* __restrict__ Bm,
    float* __restrict__ C, int M, int Nn, int K) {
  __shared__ float As[16][65];
  __shared__ float Bs[16][65];
  const int tid = threadIdx.x;
  const int tx = tid & 15, ty = tid >> 4;
  const int m0 = blockIdx.y * 64, n0 = blockIdx.x * 64;
  float acc[4][4] = {};
  for (int k0 = 0; k0 < K; k0 += 16) {
#pragma unroll
    for (int l = 0; l < 4; ++l) {
      int idx = tid + l * 256;
      int mm = idx >> 4, kk = idx & 15;
      As[kk][mm] = A[(size_t)(m0 + mm) * K + (k0 + kk)];
      Bs[kk][mm] = Bm[(size_t)(n0 + mm) * K + (k0 + kk)];
    }
    __syncthreads();
#pragma unroll
    for (int kk = 0; kk < 16; ++kk) {
      float av[4], bv[4];
#pragma unroll
      for (int i = 0; i < 4; i++) av[i] = As[kk][ty * 4 + i];
#pragma unroll
      for (int j = 0; j < 4; j++) bv[j] = Bs[kk][tx * 4 + j];
#pragma unroll
      for (int i = 0; i < 4; i++)
#pragma unroll
        for (int j = 0; j < 4; j++) acc[i][j] = fmaf(av[i], bv[j], acc[i][j]);
    }
    __syncthreads();
  }
#pragma unroll
  for (int i = 0; i < 4; i++) {
    size_t base = (size_t)(m0 + ty * 4 + i) * Nn + n0 + tx * 4;
#pragma unroll
    for (int j = 0; j < 4; j++) C[base + j] = acc[i][j];
  }
}

// ---------------- fp8 GEMM v12w: 128x192, BK=64, 8 waves, 2-buf, 40KB LDS ------------
// ALL four GEMMs. 40KB -> 4 blocks/CU = 32 waves/CU (HW max). Nn%192==0.
// Wave grid 2(M)x4(N), wave out 64x48 (acc[4][3]). 2-buf issue-ahead loop,
// slot-involution + b128 reads + K-repartition (conflict-free).
// Epilogue: Cf(+res) fp32 > Cb bf16 > C8 fp8; optional gelu.
__global__ __launch_bounds__(512) void gemm_fp8_w(
    const uchar* __restrict__ A, const uchar* __restrict__ Bw,
    const float* __restrict__ bias, const float* __restrict__ res,
    float* __restrict__ Cf, ushort* __restrict__ Cb,
    uchar* __restrict__ C8, int M, int Nn, int K, int act) {
  __shared__ uchar As[2][128][64];   // 16 KB
  __shared__ uchar Bs[2][192][64];   // 24 KB
  const int t = threadIdx.x;
  const int wid = t >> 6, l = t & 63;
  const int wm = wid >> 2, wn = wid & 3;
  const int lr = l & 15, lk = l >> 4;
  const int l4 = l >> 2, lseg = l & 3;
  const int sswz = lseg ^ ((l4 >> 1) & 3);
  const int roff = (lk ^ ((lr >> 1) & 3)) * 16;

  const int nwg = (int)gridDim.x;
  const int gx = Nn / 192;
  const int bid = (int)blockIdx.x;
  const int q = nwg >> 3, r = nwg & 7;
  const int xcd = bid & 7, sub = bid >> 3;
  const int wgid = (xcd < r ? xcd * (q + 1) : r * (q + 1) + (xcd - r) * q) + sub;
  const int m0 = (wgid / gx) * 128, n0 = (wgid % gx) * 192;

  int rA = m0 + wid * 16 + l4; rA = rA < M ? rA : M - 1;
  const uchar* gA0 = A + (size_t)rA * K + sswz * 16;
  const uchar* gB0 = Bw + (size_t)(n0 + wid * 16 + l4) * K + sswz * 16;
  const uchar* gB1 = Bw + (size_t)(n0 + 128 + wid * 16 + l4) * K + sswz * 16;  // wid<4

  f32x4 acc[4][3];
#pragma unroll
  for (int i = 0; i < 4; i++)
#pragma unroll
    for (int j = 0; j < 3; j++) acc[i][j] = (f32x4){0.f, 0.f, 0.f, 0.f};

  auto STAGE = [&](int buf, int kt) {   // 2-3 VMEM insts/thread (wave-uniform branch)
    const int k0 = kt * 64;
    GLOAD_LDS16(gA0 + k0, &As[buf][wid * 16][0]);
    GLOAD_LDS16(gB0 + k0, &Bs[buf][wid * 16][0]);
    if (wid < 4) GLOAD_LDS16(gB1 + k0, &Bs[buf][128 + wid * 16][0]);
  };

  const int NT = K >> 6;
  STAGE(0, 0);
  asm volatile("s_waitcnt vmcnt(0)" ::: "memory");
  __builtin_amdgcn_s_barrier();

  int cur = 0;
  for (int kt = 0; kt < NT; kt++) {
    if (kt + 1 < NT) STAGE(cur ^ 1, kt + 1);   // issue next-tile loads early
    long2v av[4], bv[3];
#pragma unroll
    for (int mi = 0; mi < 4; mi++)
      av[mi] = *reinterpret_cast<const long2v*>(&As[cur][wm * 64 + mi * 16 + lr][roff]);
#pragma unroll
    for (int nj = 0; nj < 3; nj++)
      bv[nj] = *reinterpret_cast<const long2v*>(&Bs[cur][wn * 48 + nj * 16 + lr][roff]);
#pragma unroll
    for (int mi = 0; mi < 4; mi++)
#pragma unroll
      for (int nj = 0; nj < 3; nj++)
        acc[mi][nj] = __builtin_amdgcn_mfma_f32_16x16x32_fp8_fp8(
            av[mi].x, bv[nj].x, acc[mi][nj], 0, 0, 0);
#pragma unroll
    for (int mi = 0; mi < 4; mi++)
#pragma unroll
      for (int nj = 0; nj < 3; nj++)
        acc[mi][nj] = __builtin_amdgcn_mfma_f32_16x16x32_fp8_fp8(
            av[mi].y, bv[nj].y, acc[mi][nj], 0, 0, 0);
    asm volatile("s_waitcnt vmcnt(0)" ::: "memory");  // prefetch landed
    __builtin_amdgcn_s_barrier();
    cur ^= 1;
  }

  // epilogue: C/D layout col=lane&15, row=(lane>>4)*4+j
#pragma unroll
  for (int mi = 0; mi < 4; mi++) {
    int rbase = m0 + wm * 64 + mi * 16 + lk * 4;
#pragma unroll
    for (int nj = 0; nj < 3; nj++) {
      int col = n0 + wn * 48 + nj * 16 + lr;
      float bvv = bias ? bias[col] : 0.f;
#pragma unroll
      for (int j = 0; j < 4; j++) {
        int row = rbase + j;
        if (row >= M) continue;
        float v = acc[mi][nj][j] + bvv;
        if (act) v = fast_gelu(v);
        size_t idx = (size_t)row * Nn + col;
        if (Cf) Cf[idx] = v + (res ? res[idx] : 0.f);
        else if (Cb) Cb[idx] = f2b(v);
        else C8[idx] = f2e4m3(v);
      }
    }
  }
}

// ---------------- attention v4: fp8 P/V, 2 blocks/CU, fp8 o output -------------------
__global__ __launch_bounds__(512) void attn4_kernel(
    const ushort* __restrict__ qkv, const float* __restrict__ asize,
    uchar* __restrict__ o8) {
  __shared__ ushort Kb[208][72];
  __shared__ uchar Vt8[64][256];
  __shared__ uchar P8[8][16][256];
  __shared__ float lb[200];
  const int bh = blockIdx.x;
  const int h = bh % H_, b = bh / H_;
  const size_t bT = (size_t)b * T_;
  const int tid = threadIdx.x;
  const int l = tid & 63, wid = tid >> 6;
  const int lr = l & 15, lk = l >> 4;

  for (int i = tid; i < 4096; i += 512) reinterpret_cast<uint*>(Vt8)[i] = 0;
  for (int i = tid; i < 8192; i += 512) reinterpret_cast<uint*>(P8)[i] = 0;
  __syncthreads();

  for (int j = tid; j < T_; j += 512) lb[j] = logf(asize[bT + j]);
  for (int idx = tid; idx < 208 * 8; idx += 512) {
    int row = idx >> 3, seg = idx & 7;
    int kr = row < T_ ? row : T_ - 1;
    *reinterpret_cast<uint4*>(&Kb[row][seg * 8]) = *reinterpret_cast<const uint4*>(
        qkv + (bT + kr) * (3 * DIM_) + DIM_ + h * HD_ + seg * 8);
  }
  for (int idx = tid; idx < 197 * 8; idx += 512) {
    int k = idx >> 3, seg = idx & 7;
    uint4 v = *reinterpret_cast<const uint4*>(
        qkv + (bT + k) * (3 * DIM_) + 2 * DIM_ + h * HD_ + seg * 8);
    const ushort* us = reinterpret_cast<const ushort*>(&v);
    const int slot = k >> 4, kin = k & 15;
#pragma unroll
    for (int e = 0; e < 8; e++) {
      int d = seg * 8 + e;
      Vt8[d][((slot ^ (d & 7)) << 4) + kin] = f2e4m3(b2f(us[e]));
    }
  }
  __syncthreads();

  for (int s = wid; s < 13; s += 8) {
    const int q0 = s * 16;
    int qr = q0 + lr; qr = qr < T_ ? qr : T_ - 1;
    const ushort* qp = qkv + (bT + qr) * (3 * DIM_) + h * HD_;
    short8 aq0 = *reinterpret_cast<const short8*>(qp + lk * 8);
    short8 aq1 = *reinterpret_cast<const short8*>(qp + 32 + lk * 8);

    f32x4 accs[13];
#pragma unroll
    for (int t2 = 0; t2 < 13; t2++) accs[t2] = (f32x4){0.f, 0.f, 0.f, 0.f};
#pragma unroll
    for (int t2 = 0; t2 < 13; t2++) {
      short8 bk0 = *reinterpret_cast<const short8*>(&Kb[t2 * 16 + lr][lk * 8]);
      short8 bk1 = *reinterpret_cast<const short8*>(&Kb[t2 * 16 + lr][32 + lk * 8]);
      accs[t2] = __builtin_amdgcn_mfma_f32_16x16x32_bf16(aq0, bk0, accs[t2], 0, 0, 0);
      accs[t2] = __builtin_amdgcn_mfma_f32_16x16x32_bf16(aq1, bk1, accs[t2], 0, 0, 0);
    }
    const int col0 = lr;
    float m4[4] = {-INFINITY, -INFINITY, -INFINITY, -INFINITY};
#pragma unroll
    for (int t2 = 0; t2 < 13; t2++) {
      int col = t2 * 16 + col0;
      bool valid = col < T_;
      float lbv = valid ? lb[col] : 0.f;
#pragma unroll
      for (int j = 0; j < 4; j++) {
        float v = valid ? fmaf(accs[t2][j], 0.125f, lbv) : -INFINITY;
        accs[t2][j] = v;
        m4[j] = fmaxf(m4[j], v);
      }
    }
#pragma unroll
    for (int off = 1; off < 16; off <<= 1)
#pragma unroll
      for (int j = 0; j < 4; j++) m4[j] = fmaxf(m4[j], __shfl_xor(m4[j], off, 64));
    float s4[4] = {0.f, 0.f, 0.f, 0.f};
#pragma unroll
    for (int t2 = 0; t2 < 13; t2++)
#pragma unroll
      for (int j = 0; j < 4; j++) {
        float e = __expf(accs[t2][j] - m4[j]);
        accs[t2][j] = e;
        s4[j] += e;
      }
#pragma unroll
    for (int off = 1; off < 16; off <<= 1)
#pragma unroll
      for (int j = 0; j < 4; j++) s4[j] += __shfl_xor(s4[j], off, 64);
    float inv4[4];
#pragma unroll
    for (int j = 0; j < 4; j++) inv4[j] = 1.0f / s4[j];
#pragma unroll
    for (int t2 = 0; t2 < 13; t2++)
#pragma unroll
      for (int j = 0; j < 4; j++) {
        int rr = lk * 4 + j;
        P8[wid][rr][((t2 ^ (rr & 7)) << 4) + col0] = f2e4m3(accs[t2][j] * inv4[j]);
      }

    f32x4 acco[4];
#pragma unroll
    for (int ct = 0; ct < 4; ct++) acco[ct] = (f32x4){0.f, 0.f, 0.f, 0.f};
#pragma unroll
    for (int i = 0; i < 4; i++) {
      const int po = ((i * 4 + lk) ^ (lr & 7)) * 16;
      long2v pa = *reinterpret_cast<const long2v*>(&P8[wid][lr][po]);
#pragma unroll
      for (int ct = 0; ct < 4; ct++) {
        long2v vb = *reinterpret_cast<const long2v*>(&Vt8[ct * 16 + lr][po]);
        acco[ct] = __builtin_amdgcn_mfma_f32_16x16x32_fp8_fp8(pa.x, vb.x, acco[ct], 0, 0, 0);
        acco[ct] = __builtin_amdgcn_mfma_f32_16x16x32_fp8_fp8(pa.y, vb.y, acco[ct], 0, 0, 0);
      }
    }
#pragma unroll
    for (int ct = 0; ct < 4; ct++)
#pragma unroll
      for (int j = 0; j < 4; j++) {
        int row = q0 + lk * 4 + j;
        if (row < T_)
          o8[(bT + row) * DIM_ + h * HD_ + ct * 16 + lr] = f2e4m3(acco[ct][j]);
      }
  }
}

// ---------------- ToMe matching (fp32, decision-critical) ----------------
__global__ __launch_bounds__(256) void match_kernel(
    const float* __restrict__ metric, const float* __restrict__ asize,
    int* __restrict__ route, float* __restrict__ nsz,
    float* __restrict__ out_ns, float* __restrict__ out_rci) {
  __shared__ float m[197][65];
  __shared__ float nmax[99];
  __shared__ int nidx[99];
  __shared__ int rnk[99];
  __shared__ int srcr[16];
  __shared__ int dstr[16];
  __shared__ int unmp[99];
  int b = blockIdx.x;
  int tid = threadIdx.x;
  int lane = tid & 63, wid = tid >> 6;

  if (tid < T_) {
    const float* mr = metric + ((size_t)b * T_ + tid) * HD_;
    float ss = 0.f;
#pragma unroll
    for (int d = 0; d < 64; d++) { float v = mr[d]; ss = fmaf(v, v, ss); }
    float nrm = sqrtf(ss);
#pragma unroll
    for (int d = 0; d < 64; d++) m[tid][d] = mr[d] / nrm;
  }
  __syncthreads();

  for (int i = wid; i < NE_; i += 4) {
    if (i == 0) {
      if (lane == 0) { nmax[0] = -INFINITY; nidx[0] = 0; }
      continue;
    }
    float bv = -INFINITY;
    int bj = 1 << 30;
    for (int j = lane; j < NO_; j += 64) {
      const float* a = m[2 * i];
      const float* bb = m[2 * j + 1];
      float sdot = 0.f;
#pragma unroll
      for (int d = 0; d < 64; d++) sdot = fmaf(a[d], bb[d], sdot);
      if (sdot > bv) { bv = sdot; bj = j; }
    }
#pragma unroll
    for (int off = 32; off; off >>= 1) {
      float ov = __shfl_down(bv, off, 64);
      int oj = __shfl_down(bj, off, 64);
      if (ov > bv || (ov == bv && oj < bj)) { bv = ov; bj = oj; }
    }
    if (lane == 0) { nmax[i] = bv; nidx[i] = bj; }
  }
  __syncthreads();

  if (tid < NE_) {
    float v = nmax[tid];
    int r = 0;
    for (int i2 = 0; i2 < NE_; i2++) {
      float v2 = nmax[i2];
      r += (v2 > v) || (v2 == v && i2 < tid);
    }
    rnk[tid] = r;
  }
  __syncthreads();
  if (tid < NE_ && rnk[tid] < REFF_) { srcr[rnk[tid]] = tid; dstr[rnk[tid]] = nidx[tid]; }
  __syncthreads();
  if (tid < NE_ && rnk[tid] >= REFF_) {
    int p = 0;
    for (int i2 = 0; i2 < tid; i2++) p += (rnk[i2] >= REFF_);
    unmp[tid] = p;
    int* rr = route + ((size_t)b * TM_ + p) * 18;
    rr[0] = 1;
    rr[1] = 2 * tid;
  }
  if (tid < NO_) {
    int d = tid;
    int* rr = route + ((size_t)b * TM_ + (NE_ - REFF_) + d) * 18;
    int cnt = 1;
    rr[1] = 2 * d + 1;
    for (int r = 0; r < REFF_; r++)
      if (dstr[r] == d) { cnt++; rr[cnt] = 2 * srcr[r]; }
    rr[0] = cnt;
  }
  __syncthreads();

  for (int row = tid; row < TM_; row += 256) {
    const int* rr = route + ((size_t)b * TM_ + row) * 18;
    int cnt = rr[0];
    float s = 0.f;
    for (int t2 = 0; t2 < cnt; t2++) s += asize[(size_t)b * T_ + rr[1 + t2]];
    out_ns[(size_t)b * TM_ + row] = s;
    nsz[(size_t)b * TM_ + row] = s;
  }
  for (int t = 1 + tid; t < T_; t += 256) {
    int val;
    if (t & 1) {
      val = (NE_ - REFF_ - 1) + ((t - 1) >> 1);
    } else {
      int i = t >> 1;
      val = (rnk[i] >= REFF_) ? (unmp[i] - 1) : ((NE_ - REFF_ - 1) + nidx[i]);
    }
    out_rci[(size_t)b * (T_ - 1) + (t - 1)] = (float)val;
  }
}

// ---------------- fused: xm = merge(x1*size)/new_size, then LN2 -> h2 fp8 ----------
__global__ __launch_bounds__(256) void merge_ln_kernel(
    const float* __restrict__ x1, const float* __restrict__ asize,
    const int* __restrict__ route, const float* __restrict__ nsz,
    const float* __restrict__ g, const float* __restrict__ bb,
    float* __restrict__ xm, uchar* __restrict__ h28) {
  int row = blockIdx.x;
  int b = row / TM_;
  const int* rr = route + (size_t)row * 18;
  __shared__ int cnt_s;
  __shared__ int toks[17];
  __shared__ float szs[17];
  __shared__ float red[4];
  int tid = threadIdx.x;
  if (tid == 0) cnt_s = rr[0];
  __syncthreads();
  int cnt = cnt_s;
  if (tid < cnt) {
    int t = rr[1 + tid];
    toks[tid] = t;
    szs[tid] = asize[(size_t)b * T_ + t];
  }
  __syncthreads();
  float ns = nsz[row];
  float val[3];
#pragma unroll
  for (int p = 0; p < 3; p++) {
    int e = tid + p * 256;
    float acc = 0.f;
    for (int c2 = 0; c2 < cnt; c2++)
      acc = fmaf(x1[((size_t)b * T_ + toks[c2]) * DIM_ + e], szs[c2], acc);
    val[p] = acc / ns;
    xm[(size_t)row * DIM_ + e] = val[p];
  }
  float s = val[0] + val[1] + val[2];
  s = block_sum(s, red);
  float mean = s * (1.0f / DIM_);
  float vs = 0.f;
#pragma unroll
  for (int p = 0; p < 3; p++) { float d = val[p] - mean; vs = fmaf(d, d, vs); }
  vs = block_sum(vs, red);
  float rstd = rsqrtf(vs * (1.0f / DIM_) + 1e-5f);
#pragma unroll
  for (int p = 0; p < 3; p++) {
    int e = tid + p * 256;
    h28[(size_t)row * DIM_ + e] = f2e4m3((val[p] - mean) * rstd * g[e] + bb[e]);
  }
}

// ---------------- launch ----------------
extern "C" void kernel_launch(void* const* d_in, const int* in_sizes, int n_in,
                              void* d_out, int out_size, void* d_ws, size_t ws_size,
                              hipStream_t stream) {
  const float* x_in = (const float*)d_in[0];
  const float* asize = (const float*)d_in[1];
  const float* ln1g = (const float*)d_in[2];
  const float* ln1b = (const float*)d_in[3];
  const float* wqkv = (const float*)d_in[4];
  const float* wproj = (const float*)d_in[5];
  const float* bproj = (const float*)d_in[6];
  const float* ln2g = (const float*)d_in[7];
  const float* ln2b = (const float*)d_in[8];
  const float* wfc1 = (const float*)d_in[9];
  const float* bfc1 = (const float*)d_in[10];
  const float* wfc2 = (const float*)d_in[11];
  const float* bfc2 = (const float*)d_in[12];

  char* base = (char*)d_ws;
  float* h    = (float*)(base + BOFF_A);
  ushort* qkvb = (ushort*)(base + BOFF_A);
  float* x1   = (float*)(base + BOFF_A);
  uchar* gbc8 = (uchar*)(base + BOFF_GBC);
  uchar* h8   = (uchar*)(base + BOFF_B);
  uchar* o8   = (uchar*)(base + BOFF_O8);
  float* xm   = (float*)(base + BOFF_C);
  float* met  = (float*)(base + BOFF_D);
  uchar* h28  = (uchar*)(base + BOFF_D);
  float* wkm  = (float*)(base + BOFF_WKM);
  int* route  = (int*)(base + BOFF_RT);
  float* nsz  = (float*)(base + BOFF_NSZ);
  uchar* w8q  = (uchar*)(base + BOFF_WQB);
  uchar* w8p  = (uchar*)(base + BOFF_WPB);
  uchar* w18  = (uchar*)(base + BOFF_W1B);
  uchar* w28  = (uchar*)(base + BOFF_W2B);

  float* out_x = (float*)d_out;
  float* out_ns = out_x + (size_t)NM_ * DIM_;
  float* out_rci = out_ns + NM_;

  f2ball_kernel<<<(SEG3 / 4 + 255) / 256, 256, 0, stream>>>(
      wqkv, wproj, wfc1, wfc2, w8q, w8p, w18, w28);
  wkmean_kernel<<<(HD_ * DIM_ + 255) / 256, 256, 0, stream>>>(wqkv, wkm);

  ln_kernel<<<N_, 256, 0, stream>>>(x_in, ln1g, ln1b, h, h8);
  gemm_bt<<<dim3(1, N_ / 64), 256, 0, stream>>>(h, wkm, met, N_, HD_, DIM_);
  // qkv: fp8 in -> bf16 out (2304/192 = 12 n-tiles)
  gemm_fp8_w<<<((N_ + 127) / 128) * (3 * DIM_ / 192), 512, 0, stream>>>(
      h8, w8q, nullptr, nullptr, nullptr, qkvb, nullptr, N_, 3 * DIM_, DIM_, 0);
  attn4_kernel<<<B_ * H_, 512, 0, stream>>>(qkvb, asize, o8);
  // proj: fp8 in -> fp32 out + residual (768/192 = 4 n-tiles)
  gemm_fp8_w<<<((N_ + 127) / 128) * (DIM_ / 192), 512, 0, stream>>>(
      o8, w8p, bproj, x_in, x1, nullptr, nullptr, N_, DIM_, DIM_, 0);
  match_kernel<<<B_, 256, 0, stream>>>(met, asize, route, nsz, out_ns, out_rci);
  merge_ln_kernel<<<NM_, 256, 0, stream>>>(x1, asize, route, nsz, ln2g, ln2b, xm, h28);

  // fc1: fp8 in/out + gelu (3072/192 = 16 n-tiles)
  gemm_fp8_w<<<((NM_ + 127) / 128) * (MLP_ / 192), 512, 0, stream>>>(
      h28, w18, bfc1, nullptr, nullptr, nullptr, gbc8, NM_, MLP_, DIM_, 1);
  // fc2: fp8 in -> fp32 out + residual (768/192 = 4 n-tiles)
  gemm_fp8_w<<<((NM_ + 127) / 128) * (DIM_ / 192), 512, 0, stream>>>(
      gbc8, w28, bfc2, xm, out_x, nullptr, nullptr, NM_, DIM_, MLP_, 0);
}

// Round 24
// 454.445 us; speedup vs baseline: 1.0111x; 1.0111x over previous
//
#include <hip/hip_runtime.h>
#include <cstdint>
#include <cstddef>

#define DEVFN __device__ __forceinline__

typedef __attribute__((ext_vector_type(8))) short short8;
typedef __attribute__((ext_vector_type(4))) float f32x4;
typedef __attribute__((ext_vector_type(2))) long long2v;

// async global->LDS, 16B per lane; LDS dest = wave-uniform base + lane*16
#define GLOAD_LDS16(gaddr, laddr)                                              \
  __builtin_amdgcn_global_load_lds(                                            \
      (const __attribute__((address_space(1))) uint32_t*)(gaddr),              \
      (__attribute__((address_space(3))) uint32_t*)(laddr), 16, 0, 0)

// Problem constants
constexpr int B_ = 64, T_ = 197, DIM_ = 768, H_ = 12, HD_ = 64, MLP_ = 3072;
constexpr int N_ = B_ * T_;          // 12608 tokens
constexpr int NE_ = 99, NO_ = 98, REFF_ = 16;
constexpr int TM_ = (NE_ - REFF_) + NO_;  // 181 merged tokens
constexpr int NM_ = B_ * TM_;        // 11584 merged rows

// ---------------- workspace layout (BYTE offsets; all 16B-aligned) ----------------
constexpr size_t BOFF_A    = 0;
constexpr size_t BOFF_GBC  = 0;            // gbc fp8: 35.6MB, overlays dead A region
constexpr size_t BOFF_B    = 58097664;     // h8 fp8 [9.68MB] then o8 fp8 [9.68MB]
constexpr size_t BOFF_O8   = 67780608;     // = BOFF_B + N_*DIM_
constexpr size_t BOFF_C    = 77463552;
constexpr size_t BOFF_D    = 113049600;    // met fp32 then h2 fp8 (disjoint lifetimes)
constexpr size_t BOFF_WKM  = 130842624;
constexpr size_t BOFF_RT   = 131039232;
constexpr size_t BOFF_NSZ  = 131873280;
constexpr size_t BOFF_WQB  = 131919616;    // fp8 wqkv
constexpr size_t BOFF_WPB  = 135458560;    // fp8 wproj
constexpr size_t BOFF_W1B  = 136638208;    // fp8
constexpr size_t BOFF_W2B  = 141356800;    // fp8

// ---------------- bf16 helpers ----------------
DEVFN ushort f2b(float f) {
  union { float f; uint u; } c; c.f = f;
  uint u = c.u;
  u = (u + 0x7FFFu + ((u >> 16) & 1u)) >> 16;
  return (ushort)u;
}
DEVFN float b2f(ushort h) {
  union { uint u; float f; } c; c.u = ((uint)h) << 16;
  return c.f;
}
// fp8 e4m3 (OCP) converts via HW
DEVFN uchar f2e4m3(float v) {
  return (uchar)__builtin_amdgcn_cvt_pk_fp8_f32(v, 0.f, 0, false);
}
DEVFN uint pk4_fp8(float a, float b, float c, float d) {
  int r = __builtin_amdgcn_cvt_pk_fp8_f32(a, b, 0, false);
  r = __builtin_amdgcn_cvt_pk_fp8_f32(c, d, r, true);
  return (uint)r;
}

// fast GELU (tanh form), clamped
DEVFN float fast_gelu(float x) {
  float x3 = x * x * x;
  float z2 = 2.0f * 0.7978845608028654f * fmaf(0.044715f, x3, x);
  z2 = fminf(fmaxf(z2, -60.0f), 60.0f);
  float e = __expf(z2);
  float th = (e - 1.0f) / (e + 1.0f);
  return 0.5f * x * (1.0f + th);
}

// ---------------- reductions ----------------
DEVFN float wave_sum(float v) {
#pragma unroll
  for (int o = 32; o; o >>= 1) v += __shfl_down(v, o, 64);
  return v;
}
DEVFN float block_sum(float v, float* red) {
  v = wave_sum(v);
  int lane = threadIdx.x & 63, wid = threadIdx.x >> 6;
  __syncthreads();
  if (lane == 0) red[wid] = v;
  __syncthreads();
  return red[0] + red[1] + red[2] + red[3];
}

// ------- fused weight conversion: all four weights -> fp8 ----------------------------
constexpr int SEG0 = 3 * DIM_ * DIM_;
constexpr int SEG1 = SEG0 + DIM_ * DIM_;
constexpr int SEG2 = SEG1 + MLP_ * DIM_;
constexpr int SEG3 = SEG2 + DIM_ * MLP_;
__global__ __launch_bounds__(256) void f2ball_kernel(
    const float* __restrict__ s0, const float* __restrict__ s1,
    const float* __restrict__ s2, const float* __restrict__ s3,
    uchar* __restrict__ d0, uchar* __restrict__ d1,
    uchar* __restrict__ d2, uchar* __restrict__ d3) {
  int i = (blockIdx.x * 256 + threadIdx.x) * 4;
  if (i >= SEG3) return;
  const float* src; uchar* dst; int off;
  if (i < SEG0)      { src = s0; dst = d0; off = i; }
  else if (i < SEG1) { src = s1; dst = d1; off = i - SEG0; }
  else if (i < SEG2) { src = s2; dst = d2; off = i - SEG1; }
  else               { src = s3; dst = d3; off = i - SEG2; }
  float4 v = *reinterpret_cast<const float4*>(src + off);
  *reinterpret_cast<uint*>(dst + off) = pk4_fp8(v.x, v.y, v.z, v.w);
}

// ---------------- LayerNorm: fp32 + fp8 outputs (LN1) ----------------
__global__ __launch_bounds__(256) void ln_kernel(
    const float* __restrict__ x, const float* __restrict__ g,
    const float* __restrict__ bb, float* __restrict__ outf,
    uchar* __restrict__ out8) {
  __shared__ float red[4];
  size_t row = blockIdx.x;
  const float* xr = x + row * DIM_;
  int tid = threadIdx.x;
  float s = 0.f;
  for (int i = tid; i < DIM_; i += 256) s += xr[i];
  s = block_sum(s, red);
  float mean = s * (1.0f / DIM_);
  float vs = 0.f;
  for (int i = tid; i < DIM_; i += 256) { float d = xr[i] - mean; vs = fmaf(d, d, vs); }
  vs = block_sum(vs, red);
  float rstd = rsqrtf(vs * (1.0f / DIM_) + 1e-5f);
  for (int i = tid; i < DIM_; i += 256) {
    float v = (xr[i] - mean) * rstd * g[i] + bb[i];
    if (outf) outf[row * DIM_ + i] = v;
    out8[row * DIM_ + i] = f2e4m3(v);
  }
}

// ---------------- head-averaged K weights ----------------
__global__ __launch_bounds__(256) void wkmean_kernel(const float* __restrict__ wqkv,
                                                     float* __restrict__ wkm) {
  int idx = blockIdx.x * 256 + threadIdx.x;
  if (idx >= HD_ * DIM_) return;
  int d = idx / DIM_, c = idx % DIM_;
  float s = 0.f;
  for (int h2 = 0; h2 < H_; h2++) s += wqkv[(size_t)(DIM_ + h2 * HD_ + d) * DIM_ + c];
  wkm[idx] = s * (1.0f / H_);
}

// ---------------- fp32 GEMM (kept for the index-deciding metric path) ----------------
__global__ __launch_bounds__(256) void gemm_bt(
    const float* __restrict__ A, const float* __restrict__ Bm,
    float* __restrict__ C, int M, int Nn, int K) {
  __shared__ float As[16][65];
  __shared__ float Bs[16][65];
  const int tid = threadIdx.x;
  const int tx = tid & 15, ty = tid >> 4;
  const int m0 = blockIdx.y * 64, n0 = blockIdx.x * 64;
  float acc[4][4] = {};
  for (int k0 = 0; k0 < K; k0 += 16) {
#pragma unroll
    for (int l = 0; l < 4; ++l) {
      int idx = tid + l * 256;
      int mm = idx >> 4, kk = idx & 15;
      As[kk][mm] = A[(size_t)(m0 + mm) * K + (k0 + kk)];
      Bs[kk][mm] = Bm[(size_t)(n0 + mm) * K + (k0 + kk)];
    }
    __syncthreads();
#pragma unroll
    for (int kk = 0; kk < 16; ++kk) {
      float av[4], bv[4];
#pragma unroll
      for (int i = 0; i < 4; i++) av[i] = As[kk][ty * 4 + i];
#pragma unroll
      for (int j = 0; j < 4; j++) bv[j] = Bs[kk][tx * 4 + j];
#pragma unroll
      for (int i = 0; i < 4; i++)
#pragma unroll
        for (int j = 0; j < 4; j++) acc[i][j] = fmaf(av[i], bv[j], acc[i][j]);
    }
    __syncthreads();
  }
#pragma unroll
  for (int i = 0; i < 4; i++) {
    size_t base = (size_t)(m0 + ty * 4 + i) * Nn + n0 + tx * 4;
#pragma unroll
    for (int j = 0; j < 4; j++) C[base + j] = acc[i][j];
  }
}

// ---------------- fp8 GEMM v12w: 128x192, BK=64, 8 waves, 2-buf, 40KB LDS ------------
// qkv & fc1. 40KB -> 4 blocks/CU = 32 waves/CU (HW max). Nn%192==0.
// Wave grid 2(M)x4(N), wave out 64x48 (acc[4][3]). Same 2-buf issue-ahead loop,
// slot-involution + b128 reads + K-repartition (conflict-free geometry unchanged).
__global__ __launch_bounds__(512) void gemm_fp8_w(
    const uchar* __restrict__ A, const uchar* __restrict__ Bw,
    const float* __restrict__ bias, ushort* __restrict__ Cb,
    uchar* __restrict__ C8, int M, int Nn, int K, int act) {
  __shared__ uchar As[2][128][64];   // 16 KB
  __shared__ uchar Bs[2][192][64];   // 24 KB
  const int t = threadIdx.x;
  const int wid = t >> 6, l = t & 63;
  const int wm = wid >> 2, wn = wid & 3;
  const int lr = l & 15, lk = l >> 4;
  const int l4 = l >> 2, lseg = l & 3;
  const int sswz = lseg ^ ((l4 >> 1) & 3);
  const int roff = (lk ^ ((lr >> 1) & 3)) * 16;

  const int nwg = (int)gridDim.x;
  const int gx = Nn / 192;
  const int bid = (int)blockIdx.x;
  const int q = nwg >> 3, r = nwg & 7;
  const int xcd = bid & 7, sub = bid >> 3;
  const int wgid = (xcd < r ? xcd * (q + 1) : r * (q + 1) + (xcd - r) * q) + sub;
  const int m0 = (wgid / gx) * 128, n0 = (wgid % gx) * 192;

  int rA = m0 + wid * 16 + l4; rA = rA < M ? rA : M - 1;
  const uchar* gA0 = A + (size_t)rA * K + sswz * 16;
  const uchar* gB0 = Bw + (size_t)(n0 + wid * 16 + l4) * K + sswz * 16;
  const uchar* gB1 = Bw + (size_t)(n0 + 128 + wid * 16 + l4) * K + sswz * 16;  // wid<4

  f32x4 acc[4][3];
#pragma unroll
  for (int i = 0; i < 4; i++)
#pragma unroll
    for (int j = 0; j < 3; j++) acc[i][j] = (f32x4){0.f, 0.f, 0.f, 0.f};

  auto STAGE = [&](int buf, int kt) {   // 2-3 VMEM insts/thread (wave-uniform branch)
    const int k0 = kt * 64;
    GLOAD_LDS16(gA0 + k0, &As[buf][wid * 16][0]);
    GLOAD_LDS16(gB0 + k0, &Bs[buf][wid * 16][0]);
    if (wid < 4) GLOAD_LDS16(gB1 + k0, &Bs[buf][128 + wid * 16][0]);
  };

  const int NT = K >> 6;
  STAGE(0, 0);
  asm volatile("s_waitcnt vmcnt(0)" ::: "memory");
  __builtin_amdgcn_s_barrier();

  int cur = 0;
  for (int kt = 0; kt < NT; kt++) {
    if (kt + 1 < NT) STAGE(cur ^ 1, kt + 1);   // issue next-tile loads early
    long2v av[4], bv[3];
#pragma unroll
    for (int mi = 0; mi < 4; mi++)
      av[mi] = *reinterpret_cast<const long2v*>(&As[cur][wm * 64 + mi * 16 + lr][roff]);
#pragma unroll
    for (int nj = 0; nj < 3; nj++)
      bv[nj] = *reinterpret_cast<const long2v*>(&Bs[cur][wn * 48 + nj * 16 + lr][roff]);
#pragma unroll
    for (int mi = 0; mi < 4; mi++)
#pragma unroll
      for (int nj = 0; nj < 3; nj++)
        acc[mi][nj] = __builtin_amdgcn_mfma_f32_16x16x32_fp8_fp8(
            av[mi].x, bv[nj].x, acc[mi][nj], 0, 0, 0);
#pragma unroll
    for (int mi = 0; mi < 4; mi++)
#pragma unroll
      for (int nj = 0; nj < 3; nj++)
        acc[mi][nj] = __builtin_amdgcn_mfma_f32_16x16x32_fp8_fp8(
            av[mi].y, bv[nj].y, acc[mi][nj], 0, 0, 0);
    asm volatile("s_waitcnt vmcnt(0)" ::: "memory");  // prefetch landed
    __builtin_amdgcn_s_barrier();
    cur ^= 1;
  }

  // epilogue: C/D layout col=lane&15, row=(lane>>4)*4+j
#pragma unroll
  for (int mi = 0; mi < 4; mi++) {
    int rbase = m0 + wm * 64 + mi * 16 + lk * 4;
#pragma unroll
    for (int nj = 0; nj < 3; nj++) {
      int col = n0 + wn * 48 + nj * 16 + lr;
      float bvv = bias ? bias[col] : 0.f;
#pragma unroll
      for (int j = 0; j < 4; j++) {
        int row = rbase + j;
        if (row >= M) continue;
        float v = acc[mi][nj][j] + bvv;
        if (act) v = fast_gelu(v);
        size_t idx = (size_t)row * Nn + col;
        if (Cb) Cb[idx] = f2b(v);
        else C8[idx] = f2e4m3(v);
      }
    }
  }
}

// ---------------- fp8 GEMM v11: 128x128, BK=64, 4 waves, 2-buf — proj & fc2 ----------
__global__ __launch_bounds__(256) void gemm_fp8(
    const uchar* __restrict__ A, const uchar* __restrict__ Bw,
    const float* __restrict__ bias, const float* __restrict__ res,
    float* __restrict__ Cf, int M, int Nn, int K) {
  __shared__ uchar As[2][128][64];   // 16 KB
  __shared__ uchar Bs[2][128][64];   // 16 KB
  const int t = threadIdx.x;
  const int wid = t >> 6, l = t & 63;
  const int wrow = wid >> 1, wcol = wid & 1;
  const int lr = l & 15, lk = l >> 4;
  const int l4 = l >> 2, lseg = l & 3;
  const int sswz = lseg ^ ((l4 >> 1) & 3);
  const int roff = (lk ^ ((lr >> 1) & 3)) * 16;

  const int nwg = (int)gridDim.x;
  const int gx = Nn >> 7;
  const int bid = (int)blockIdx.x;
  const int q = nwg >> 3, r = nwg & 7;
  const int xcd = bid & 7, sub = bid >> 3;
  const int wgid = (xcd < r ? xcd * (q + 1) : r * (q + 1) + (xcd - r) * q) + sub;
  const int m0 = (wgid / gx) * 128, n0 = (wgid % gx) * 128;

  int rA0 = m0 + wid * 32 + l4;      rA0 = rA0 < M ? rA0 : M - 1;
  int rA1 = m0 + wid * 32 + 16 + l4; rA1 = rA1 < M ? rA1 : M - 1;
  const uchar* gA0 = A + (size_t)rA0 * K + sswz * 16;
  const uchar* gA1 = A + (size_t)rA1 * K + sswz * 16;
  const uchar* gB0 = Bw + (size_t)(n0 + wid * 32 + l4) * K + sswz * 16;
  const uchar* gB1 = Bw + (size_t)(n0 + wid * 32 + 16 + l4) * K + sswz * 16;

  f32x4 acc[4][4];
#pragma unroll
  for (int i = 0; i < 4; i++)
#pragma unroll
    for (int j = 0; j < 4; j++) acc[i][j] = (f32x4){0.f, 0.f, 0.f, 0.f};

  auto STAGE = [&](int buf, int kt) {   // 4 VMEM insts/thread
    const int k0 = kt * 64;
    GLOAD_LDS16(gA0 + k0, &As[buf][wid * 32][0]);
    GLOAD_LDS16(gB0 + k0, &Bs[buf][wid * 32][0]);
    GLOAD_LDS16(gA1 + k0, &As[buf][wid * 32 + 16][0]);
    GLOAD_LDS16(gB1 + k0, &Bs[buf][wid * 32 + 16][0]);
  };

  const int NT = K >> 6;
  STAGE(0, 0);
  asm volatile("s_waitcnt vmcnt(0)" ::: "memory");
  __builtin_amdgcn_s_barrier();

  int cur = 0;
  for (int kt = 0; kt < NT; kt++) {
    if (kt + 1 < NT) STAGE(cur ^ 1, kt + 1);   // issue next-tile loads early
    long2v av[4], bv[4];
#pragma unroll
    for (int mi = 0; mi < 4; mi++)
      av[mi] = *reinterpret_cast<const long2v*>(&As[cur][wrow * 64 + mi * 16 + lr][roff]);
#pragma unroll
    for (int nj = 0; nj < 4; nj++)
      bv[nj] = *reinterpret_cast<const long2v*>(&Bs[cur][wcol * 64 + nj * 16 + lr][roff]);
#pragma unroll
    for (int mi = 0; mi < 4; mi++)
#pragma unroll
      for (int nj = 0; nj < 4; nj++)
        acc[mi][nj] = __builtin_amdgcn_mfma_f32_16x16x32_fp8_fp8(
            av[mi].x, bv[nj].x, acc[mi][nj], 0, 0, 0);
#pragma unroll
    for (int mi = 0; mi < 4; mi++)
#pragma unroll
      for (int nj = 0; nj < 4; nj++)
        acc[mi][nj] = __builtin_amdgcn_mfma_f32_16x16x32_fp8_fp8(
            av[mi].y, bv[nj].y, acc[mi][nj], 0, 0, 0);
    asm volatile("s_waitcnt vmcnt(0)" ::: "memory");  // prefetch landed
    __builtin_amdgcn_s_barrier();
    cur ^= 1;
  }

#pragma unroll
  for (int mi = 0; mi < 4; mi++) {
    int rbase = m0 + wrow * 64 + mi * 16 + lk * 4;
#pragma unroll
    for (int nj = 0; nj < 4; nj++) {
      int col = n0 + wcol * 64 + nj * 16 + lr;
      float bvv = bias[col];
#pragma unroll
      for (int j = 0; j < 4; j++) {
        int row = rbase + j;
        if (row >= M) continue;
        size_t idx = (size_t)row * Nn + col;
        Cf[idx] = acc[mi][nj][j] + bvv + res[idx];
      }
    }
  }
}

// ---------------- attention v4: fp8 P/V, 2 blocks/CU, fp8 o output -------------------
__global__ __launch_bounds__(512) void attn4_kernel(
    const ushort* __restrict__ qkv, const float* __restrict__ asize,
    uchar* __restrict__ o8) {
  __shared__ ushort Kb[208][72];
  __shared__ uchar Vt8[64][256];
  __shared__ uchar P8[8][16][256];
  __shared__ float lb[200];
  const int bh = blockIdx.x;
  const int h = bh % H_, b = bh / H_;
  const size_t bT = (size_t)b * T_;
  const int tid = threadIdx.x;
  const int l = tid & 63, wid = tid >> 6;
  const int lr = l & 15, lk = l >> 4;

  for (int i = tid; i < 4096; i += 512) reinterpret_cast<uint*>(Vt8)[i] = 0;
  for (int i = tid; i < 8192; i += 512) reinterpret_cast<uint*>(P8)[i] = 0;
  __syncthreads();

  for (int j = tid; j < T_; j += 512) lb[j] = logf(asize[bT + j]);
  for (int idx = tid; idx < 208 * 8; idx += 512) {
    int row = idx >> 3, seg = idx & 7;
    int kr = row < T_ ? row : T_ - 1;
    *reinterpret_cast<uint4*>(&Kb[row][seg * 8]) = *reinterpret_cast<const uint4*>(
        qkv + (bT + kr) * (3 * DIM_) + DIM_ + h * HD_ + seg * 8);
  }
  for (int idx = tid; idx < 197 * 8; idx += 512) {
    int k = idx >> 3, seg = idx & 7;
    uint4 v = *reinterpret_cast<const uint4*>(
        qkv + (bT + k) * (3 * DIM_) + 2 * DIM_ + h * HD_ + seg * 8);
    const ushort* us = reinterpret_cast<const ushort*>(&v);
    const int slot = k >> 4, kin = k & 15;
#pragma unroll
    for (int e = 0; e < 8; e++) {
      int d = seg * 8 + e;
      Vt8[d][((slot ^ (d & 7)) << 4) + kin] = f2e4m3(b2f(us[e]));
    }
  }
  __syncthreads();

  for (int s = wid; s < 13; s += 8) {
    const int q0 = s * 16;
    int qr = q0 + lr; qr = qr < T_ ? qr : T_ - 1;
    const ushort* qp = qkv + (bT + qr) * (3 * DIM_) + h * HD_;
    short8 aq0 = *reinterpret_cast<const short8*>(qp + lk * 8);
    short8 aq1 = *reinterpret_cast<const short8*>(qp + 32 + lk * 8);

    f32x4 accs[13];
#pragma unroll
    for (int t2 = 0; t2 < 13; t2++) accs[t2] = (f32x4){0.f, 0.f, 0.f, 0.f};
#pragma unroll
    for (int t2 = 0; t2 < 13; t2++) {
      short8 bk0 = *reinterpret_cast<const short8*>(&Kb[t2 * 16 + lr][lk * 8]);
      short8 bk1 = *reinterpret_cast<const short8*>(&Kb[t2 * 16 + lr][32 + lk * 8]);
      accs[t2] = __builtin_amdgcn_mfma_f32_16x16x32_bf16(aq0, bk0, accs[t2], 0, 0, 0);
      accs[t2] = __builtin_amdgcn_mfma_f32_16x16x32_bf16(aq1, bk1, accs[t2], 0, 0, 0);
    }
    const int col0 = lr;
    float m4[4] = {-INFINITY, -INFINITY, -INFINITY, -INFINITY};
#pragma unroll
    for (int t2 = 0; t2 < 13; t2++) {
      int col = t2 * 16 + col0;
      bool valid = col < T_;
      float lbv = valid ? lb[col] : 0.f;
#pragma unroll
      for (int j = 0; j < 4; j++) {
        float v = valid ? fmaf(accs[t2][j], 0.125f, lbv) : -INFINITY;
        accs[t2][j] = v;
        m4[j] = fmaxf(m4[j], v);
      }
    }
#pragma unroll
    for (int off = 1; off < 16; off <<= 1)
#pragma unroll
      for (int j = 0; j < 4; j++) m4[j] = fmaxf(m4[j], __shfl_xor(m4[j], off, 64));
    float s4[4] = {0.f, 0.f, 0.f, 0.f};
#pragma unroll
    for (int t2 = 0; t2 < 13; t2++)
#pragma unroll
      for (int j = 0; j < 4; j++) {
        float e = __expf(accs[t2][j] - m4[j]);
        accs[t2][j] = e;
        s4[j] += e;
      }
#pragma unroll
    for (int off = 1; off < 16; off <<= 1)
#pragma unroll
      for (int j = 0; j < 4; j++) s4[j] += __shfl_xor(s4[j], off, 64);
    float inv4[4];
#pragma unroll
    for (int j = 0; j < 4; j++) inv4[j] = 1.0f / s4[j];
#pragma unroll
    for (int t2 = 0; t2 < 13; t2++)
#pragma unroll
      for (int j = 0; j < 4; j++) {
        int rr = lk * 4 + j;
        P8[wid][rr][((t2 ^ (rr & 7)) << 4) + col0] = f2e4m3(accs[t2][j] * inv4[j]);
      }

    f32x4 acco[4];
#pragma unroll
    for (int ct = 0; ct < 4; ct++) acco[ct] = (f32x4){0.f, 0.f, 0.f, 0.f};
#pragma unroll
    for (int i = 0; i < 4; i++) {
      const int po = ((i * 4 + lk) ^ (lr & 7)) * 16;
      long2v pa = *reinterpret_cast<const long2v*>(&P8[wid][lr][po]);
#pragma unroll
      for (int ct = 0; ct < 4; ct++) {
        long2v vb = *reinterpret_cast<const long2v*>(&Vt8[ct * 16 + lr][po]);
        acco[ct] = __builtin_amdgcn_mfma_f32_16x16x32_fp8_fp8(pa.x, vb.x, acco[ct], 0, 0, 0);
        acco[ct] = __builtin_amdgcn_mfma_f32_16x16x32_fp8_fp8(pa.y, vb.y, acco[ct], 0, 0, 0);
      }
    }
#pragma unroll
    for (int ct = 0; ct < 4; ct++)
#pragma unroll
      for (int j = 0; j < 4; j++) {
        int row = q0 + lk * 4 + j;
        if (row < T_)
          o8[(bT + row) * DIM_ + h * HD_ + ct * 16 + lr] = f2e4m3(acco[ct][j]);
      }
  }
}

// ---------------- ToMe matching (fp32, decision-critical) ----------------
__global__ __launch_bounds__(256) void match_kernel(
    const float* __restrict__ metric, const float* __restrict__ asize,
    int* __restrict__ route, float* __restrict__ nsz,
    float* __restrict__ out_ns, float* __restrict__ out_rci) {
  __shared__ float m[197][65];
  __shared__ float nmax[99];
  __shared__ int nidx[99];
  __shared__ int rnk[99];
  __shared__ int srcr[16];
  __shared__ int dstr[16];
  __shared__ int unmp[99];
  int b = blockIdx.x;
  int tid = threadIdx.x;
  int lane = tid & 63, wid = tid >> 6;

  if (tid < T_) {
    const float* mr = metric + ((size_t)b * T_ + tid) * HD_;
    float ss = 0.f;
#pragma unroll
    for (int d = 0; d < 64; d++) { float v = mr[d]; ss = fmaf(v, v, ss); }
    float nrm = sqrtf(ss);
#pragma unroll
    for (int d = 0; d < 64; d++) m[tid][d] = mr[d] / nrm;
  }
  __syncthreads();

  for (int i = wid; i < NE_; i += 4) {
    if (i == 0) {
      if (lane == 0) { nmax[0] = -INFINITY; nidx[0] = 0; }
      continue;
    }
    float bv = -INFINITY;
    int bj = 1 << 30;
    for (int j = lane; j < NO_; j += 64) {
      const float* a = m[2 * i];
      const float* bb = m[2 * j + 1];
      float sdot = 0.f;
#pragma unroll
      for (int d = 0; d < 64; d++) sdot = fmaf(a[d], bb[d], sdot);
      if (sdot > bv) { bv = sdot; bj = j; }
    }
#pragma unroll
    for (int off = 32; off; off >>= 1) {
      float ov = __shfl_down(bv, off, 64);
      int oj = __shfl_down(bj, off, 64);
      if (ov > bv || (ov == bv && oj < bj)) { bv = ov; bj = oj; }
    }
    if (lane == 0) { nmax[i] = bv; nidx[i] = bj; }
  }
  __syncthreads();

  if (tid < NE_) {
    float v = nmax[tid];
    int r = 0;
    for (int i2 = 0; i2 < NE_; i2++) {
      float v2 = nmax[i2];
      r += (v2 > v) || (v2 == v && i2 < tid);
    }
    rnk[tid] = r;
  }
  __syncthreads();
  if (tid < NE_ && rnk[tid] < REFF_) { srcr[rnk[tid]] = tid; dstr[rnk[tid]] = nidx[tid]; }
  __syncthreads();
  if (tid < NE_ && rnk[tid] >= REFF_) {
    int p = 0;
    for (int i2 = 0; i2 < tid; i2++) p += (rnk[i2] >= REFF_);
    unmp[tid] = p;
    int* rr = route + ((size_t)b * TM_ + p) * 18;
    rr[0] = 1;
    rr[1] = 2 * tid;
  }
  if (tid < NO_) {
    int d = tid;
    int* rr = route + ((size_t)b * TM_ + (NE_ - REFF_) + d) * 18;
    int cnt = 1;
    rr[1] = 2 * d + 1;
    for (int r = 0; r < REFF_; r++)
      if (dstr[r] == d) { cnt++; rr[cnt] = 2 * srcr[r]; }
    rr[0] = cnt;
  }
  __syncthreads();

  for (int row = tid; row < TM_; row += 256) {
    const int* rr = route + ((size_t)b * TM_ + row) * 18;
    int cnt = rr[0];
    float s = 0.f;
    for (int t2 = 0; t2 < cnt; t2++) s += asize[(size_t)b * T_ + rr[1 + t2]];
    out_ns[(size_t)b * TM_ + row] = s;
    nsz[(size_t)b * TM_ + row] = s;
  }
  for (int t = 1 + tid; t < T_; t += 256) {
    int val;
    if (t & 1) {
      val = (NE_ - REFF_ - 1) + ((t - 1) >> 1);
    } else {
      int i = t >> 1;
      val = (rnk[i] >= REFF_) ? (unmp[i] - 1) : ((NE_ - REFF_ - 1) + nidx[i]);
    }
    out_rci[(size_t)b * (T_ - 1) + (t - 1)] = (float)val;
  }
}

// ---------------- fused: xm = merge(x1*size)/new_size, then LN2 -> h2 fp8 ----------
__global__ __launch_bounds__(256) void merge_ln_kernel(
    const float* __restrict__ x1, const float* __restrict__ asize,
    const int* __restrict__ route, const float* __restrict__ nsz,
    const float* __restrict__ g, const float* __restrict__ bb,
    float* __restrict__ xm, uchar* __restrict__ h28) {
  int row = blockIdx.x;
  int b = row / TM_;
  const int* rr = route + (size_t)row * 18;
  __shared__ int cnt_s;
  __shared__ int toks[17];
  __shared__ float szs[17];
  __shared__ float red[4];
  int tid = threadIdx.x;
  if (tid == 0) cnt_s = rr[0];
  __syncthreads();
  int cnt = cnt_s;
  if (tid < cnt) {
    int t = rr[1 + tid];
    toks[tid] = t;
    szs[tid] = asize[(size_t)b * T_ + t];
  }
  __syncthreads();
  float ns = nsz[row];
  float val[3];
#pragma unroll
  for (int p = 0; p < 3; p++) {
    int e = tid + p * 256;
    float acc = 0.f;
    for (int c2 = 0; c2 < cnt; c2++)
      acc = fmaf(x1[((size_t)b * T_ + toks[c2]) * DIM_ + e], szs[c2], acc);
    val[p] = acc / ns;
    xm[(size_t)row * DIM_ + e] = val[p];
  }
  float s = val[0] + val[1] + val[2];
  s = block_sum(s, red);
  float mean = s * (1.0f / DIM_);
  float vs = 0.f;
#pragma unroll
  for (int p = 0; p < 3; p++) { float d = val[p] - mean; vs = fmaf(d, d, vs); }
  vs = block_sum(vs, red);
  float rstd = rsqrtf(vs * (1.0f / DIM_) + 1e-5f);
#pragma unroll
  for (int p = 0; p < 3; p++) {
    int e = tid + p * 256;
    h28[(size_t)row * DIM_ + e] = f2e4m3((val[p] - mean) * rstd * g[e] + bb[e]);
  }
}

// ---------------- launch ----------------
extern "C" void kernel_launch(void* const* d_in, const int* in_sizes, int n_in,
                              void* d_out, int out_size, void* d_ws, size_t ws_size,
                              hipStream_t stream) {
  const float* x_in = (const float*)d_in[0];
  const float* asize = (const float*)d_in[1];
  const float* ln1g = (const float*)d_in[2];
  const float* ln1b = (const float*)d_in[3];
  const float* wqkv = (const float*)d_in[4];
  const float* wproj = (const float*)d_in[5];
  const float* bproj = (const float*)d_in[6];
  const float* ln2g = (const float*)d_in[7];
  const float* ln2b = (const float*)d_in[8];
  const float* wfc1 = (const float*)d_in[9];
  const float* bfc1 = (const float*)d_in[10];
  const float* wfc2 = (const float*)d_in[11];
  const float* bfc2 = (const float*)d_in[12];

  char* base = (char*)d_ws;
  float* h    = (float*)(base + BOFF_A);
  ushort* qkvb = (ushort*)(base + BOFF_A);
  float* x1   = (float*)(base + BOFF_A);
  uchar* gbc8 = (uchar*)(base + BOFF_GBC);
  uchar* h8   = (uchar*)(base + BOFF_B);
  uchar* o8   = (uchar*)(base + BOFF_O8);
  float* xm   = (float*)(base + BOFF_C);
  float* met  = (float*)(base + BOFF_D);
  uchar* h28  = (uchar*)(base + BOFF_D);
  float* wkm  = (float*)(base + BOFF_WKM);
  int* route  = (int*)(base + BOFF_RT);
  float* nsz  = (float*)(base + BOFF_NSZ);
  uchar* w8q  = (uchar*)(base + BOFF_WQB);
  uchar* w8p  = (uchar*)(base + BOFF_WPB);
  uchar* w18  = (uchar*)(base + BOFF_W1B);
  uchar* w28  = (uchar*)(base + BOFF_W2B);

  float* out_x = (float*)d_out;
  float* out_ns = out_x + (size_t)NM_ * DIM_;
  float* out_rci = out_ns + NM_;

  f2ball_kernel<<<(SEG3 / 4 + 255) / 256, 256, 0, stream>>>(
      wqkv, wproj, wfc1, wfc2, w8q, w8p, w18, w28);
  wkmean_kernel<<<(HD_ * DIM_ + 255) / 256, 256, 0, stream>>>(wqkv, wkm);

  ln_kernel<<<N_, 256, 0, stream>>>(x_in, ln1g, ln1b, h, h8);
  gemm_bt<<<dim3(1, N_ / 64), 256, 0, stream>>>(h, wkm, met, N_, HD_, DIM_);
  // qkv: 128x192 tiles (2304/192 = 12)
  gemm_fp8_w<<<((N_ + 127) / 128) * (3 * DIM_ / 192), 512, 0, stream>>>(
      h8, w8q, nullptr, qkvb, nullptr, N_, 3 * DIM_, DIM_, 0);
  attn4_kernel<<<B_ * H_, 512, 0, stream>>>(qkvb, asize, o8);
  gemm_fp8<<<(DIM_ / 128) * ((N_ + 127) / 128), 256, 0, stream>>>(
      o8, w8p, bproj, x_in, x1, N_, DIM_, DIM_);
  match_kernel<<<B_, 256, 0, stream>>>(met, asize, route, nsz, out_ns, out_rci);
  merge_ln_kernel<<<NM_, 256, 0, stream>>>(x1, asize, route, nsz, ln2g, ln2b, xm, h28);

  // fc1: 128x192 tiles (3072/192 = 16)
  gemm_fp8_w<<<((NM_ + 127) / 128) * (MLP_ / 192), 512, 0, stream>>>(
      h28, w18, bfc1, nullptr, gbc8, NM_, MLP_, DIM_, 1);
  gemm_fp8<<<(DIM_ / 128) * ((NM_ + 127) / 128), 256, 0, stream>>>(
      gbc8, w28, bfc2, xm, out_x, NM_, DIM_, MLP_);
}